// Round 3
// baseline (250.236 us; speedup 1.0000x reference)
//
#include <hip/hip_runtime.h>

typedef __attribute__((ext_vector_type(8))) short short8;
typedef __attribute__((ext_vector_type(4))) float f32x4;

constexpr int SEQ = 16384, BATCH = 8, DIN = 256, NQKV = 768;
constexpr float SCALE = 0.17677669529663687f; // 32^-0.5
constexpr float EPS = 1e-5f;

__device__ __forceinline__ unsigned short f2bf(float f){
  unsigned int u = __float_as_uint(f);
  u = u + 0x7fffu + ((u >> 16) & 1u);   // RNE
  return (unsigned short)(u >> 16);
}
__device__ __forceinline__ float bf2f(unsigned short h){
  return __uint_as_float(((unsigned int)h) << 16);
}
__device__ __forceinline__ void gload_lds16(const void* g, void* l){
  __builtin_amdgcn_global_load_lds(
    (const __attribute__((address_space(1))) unsigned int*)g,
    (__attribute__((address_space(3))) unsigned int*)l, 16, 0, 0);
}

// ---- K0: Wqkv [256 x 768] fp32 -> WT [768 x 256] bf16 (transposed) ----
__global__ void k_wt(const float* __restrict__ W, unsigned short* __restrict__ WT){
  int id = blockIdx.x * 256 + threadIdx.x;
  int k = id / NQKV, n = id % NQKV;
  WT[n * DIN + k] = f2bf(W[id]);
}

// ---- K1: fused qkv GEMM + q-softmax + k-exp + context partials ----
// 1024 blocks x 256 thr (4 waves). Wave owns 32 rows; A frags in registers.
// B panels: 64 cols x K=256 = 32 KB LDS, XOR-swizzled, register-prefetched.
__global__ __launch_bounds__(256, 2) void k_qkv(const float* __restrict__ X,
                                                const unsigned short* __restrict__ WT,
                                                unsigned short* __restrict__ Q,
                                                float* __restrict__ ctxp,
                                                float* __restrict__ sumwp){
  __shared__ unsigned short Bs[64 * 256];      // 32 KB, swizzled byte^=((n&7)<<4)
  __shared__ unsigned short WVs[2][64][136];   // w^T / v^T, 34 KB, 16B-aligned stride
  __shared__ float sumLds[256];

  const int blk = blockIdx.x;
  const size_t m0 = (size_t)blk * 128;
  const int tid = threadIdx.x, wave = tid >> 6, lane = tid & 63;
  const int lg = lane >> 4, li = lane & 15;

  if (tid < 256) sumLds[tid] = 0.f;

  int4 pf[8];
  auto pfIssue = [&](int n0){
    const char* src = (const char*)WT + (size_t)n0 * 512;
    #pragma unroll
    for (int r2 = 0; r2 < 8; r2++)
      pf[r2] = *reinterpret_cast<const int4*>(src + r2 * 4096 + tid * 16);
  };
  auto pfWrite = [&](){
    #pragma unroll
    for (int r2 = 0; r2 < 8; r2++){
      int L = r2 * 4096 + tid * 16;
      int P = L ^ (((L >> 9) & 7) << 4);
      *reinterpret_cast<int4*>((char*)Bs + P) = pf[r2];
    }
  };

  // ---- prologue: prefetch panel 0, load A fragments (x fp32 -> bf16, in regs) ----
  pfIssue(256);
  short8 afrag[2][8];
  #pragma unroll
  for (int rt = 0; rt < 2; rt++){
    const float* xr = X + (m0 + wave * 32 + rt * 16 + li) * DIN + lg * 8;
    #pragma unroll
    for (int ks = 0; ks < 8; ks++){
      float4 f0 = *reinterpret_cast<const float4*>(xr + ks * 32);
      float4 f1 = *reinterpret_cast<const float4*>(xr + ks * 32 + 4);
      short8 a;
      a[0] = f2bf(f0.x); a[1] = f2bf(f0.y); a[2] = f2bf(f0.z); a[3] = f2bf(f0.w);
      a[4] = f2bf(f1.x); a[5] = f2bf(f1.y); a[6] = f2bf(f1.z); a[7] = f2bf(f1.w);
      afrag[rt][ks] = a;
    }
  }
  pfWrite();
  __syncthreads();

  f32x4 acc[2][4];
  const f32x4 zf = {0.f, 0.f, 0.f, 0.f};

  auto panelMM = [&](){
    #pragma unroll
    for (int rt = 0; rt < 2; rt++)
      #pragma unroll
      for (int j = 0; j < 4; j++) acc[rt][j] = zf;
    #pragma unroll
    for (int ks = 0; ks < 8; ks++)
      #pragma unroll
      for (int j = 0; j < 4; j++){
        int n = j * 16 + li;
        int L = n * 512 + (ks * 32 + lg * 8) * 2;
        short8 bb = *reinterpret_cast<const short8*>((const char*)Bs + (L ^ ((n & 7) << 4)));
        acc[0][j] = __builtin_amdgcn_mfma_f32_16x16x32_bf16(afrag[0][ks], bb, acc[0][j], 0, 0, 0);
        acc[1][j] = __builtin_amdgcn_mfma_f32_16x16x32_bf16(afrag[1][ks], bb, acc[1][j], 0, 0, 0);
      }
  };

  auto kEpi = [&](int p){
    #pragma unroll
    for (int j = 0; j < 4; j++){
      float cs = 0.f;
      #pragma unroll
      for (int rt = 0; rt < 2; rt++){
        float w0 = bf2f(f2bf(__expf(acc[rt][j][0])));
        float w1 = bf2f(f2bf(__expf(acc[rt][j][1])));
        float w2 = bf2f(f2bf(__expf(acc[rt][j][2])));
        float w3 = bf2f(f2bf(__expf(acc[rt][j][3])));
        ushort4 pk;
        pk.x = f2bf(w0); pk.y = f2bf(w1); pk.z = f2bf(w2); pk.w = f2bf(w3);
        cs += w0 + w1 + w2 + w3;
        *reinterpret_cast<ushort4*>(&WVs[0][j * 16 + li][wave * 32 + rt * 16 + lg * 4]) = pk;
      }
      cs += __shfl_xor(cs, 16); cs += __shfl_xor(cs, 32);
      if (lane < 16) atomicAdd(&sumLds[p * 64 + j * 16 + li], cs);
    }
  };

  auto vEpi = [&](){
    #pragma unroll
    for (int j = 0; j < 4; j++)
      #pragma unroll
      for (int rt = 0; rt < 2; rt++){
        ushort4 pk;
        pk.x = f2bf(acc[rt][j][0]); pk.y = f2bf(acc[rt][j][1]);
        pk.z = f2bf(acc[rt][j][2]); pk.w = f2bf(acc[rt][j][3]);
        *reinterpret_cast<ushort4*>(&WVs[1][j * 16 + li][wave * 32 + rt * 16 + lg * 4]) = pk;
      }
  };

  // ctx[head][d][e] = sum_tokens w^T[d][t] * v^T[e][t]  (K = 128 tokens, MFMA)
  auto ctxPhase = [&](int p){
    #pragma unroll
    for (int t2 = 0; t2 < 2; t2++){
      int tile = wave * 2 + t2;
      int hi = tile >> 2, dh = (tile >> 1) & 1, eh = tile & 1;
      int arow = hi * 32 + dh * 16 + li, brow = hi * 32 + eh * 16 + li;
      f32x4 c = zf;
      #pragma unroll
      for (int ks = 0; ks < 4; ks++){
        short8 aw = *reinterpret_cast<const short8*>(&WVs[0][arow][ks * 32 + lg * 8]);
        short8 bv = *reinterpret_cast<const short8*>(&WVs[1][brow][ks * 32 + lg * 8]);
        c = __builtin_amdgcn_mfma_f32_16x16x32_bf16(aw, bv, c, 0, 0, 0);
      }
      float* cp = ctxp + ((size_t)blk * 8 + p * 2 + hi) * 1024;
      #pragma unroll
      for (int r = 0; r < 4; r++)
        cp[(dh * 16 + lg * 4 + r) * 32 + eh * 16 + li] = c[r];
    }
  };

  auto qEpi = [&](int p){
    #pragma unroll
    for (int rt = 0; rt < 2; rt++){
      unsigned short* qp = Q + (m0 + wave * 32 + rt * 16 + lg * 4) * 256 + p * 64;
      #pragma unroll
      for (int r = 0; r < 4; r++){
        float a0 = acc[rt][0][r], a1 = acc[rt][1][r];
        float b0 = acc[rt][2][r], b1 = acc[rt][3][r];
        float mA = fmaxf(a0, a1), mB = fmaxf(b0, b1);
        #pragma unroll
        for (int mm = 1; mm < 16; mm <<= 1){
          mA = fmaxf(mA, __shfl_xor(mA, mm)); mB = fmaxf(mB, __shfl_xor(mB, mm));
        }
        float e0 = __expf(a0 - mA), e1 = __expf(a1 - mA);
        float e2 = __expf(b0 - mB), e3 = __expf(b1 - mB);
        float sA = e0 + e1, sB = e2 + e3;
        #pragma unroll
        for (int mm = 1; mm < 16; mm <<= 1){
          sA += __shfl_xor(sA, mm); sB += __shfl_xor(sB, mm);
        }
        float iA = SCALE / sA, iB = SCALE / sB;
        unsigned short* rp = qp + r * 256;
        rp[li]      = f2bf(e0 * iA);
        rp[16 + li] = f2bf(e1 * iA);
        rp[32 + li] = f2bf(e2 * iB);
        rp[48 + li] = f2bf(e3 * iB);
      }
    }
  };

  // panel order: K0 V0 c0 K1 V1 c1 K2 V2 c2 K3 V3 c3 Q0 Q1 Q2 Q3
  const int order[12] = {256, 512, 320, 576, 384, 640, 448, 704, 0, 64, 128, 192};
  #pragma unroll
  for (int pi = 0; pi < 12; pi++){
    if (pi < 11) pfIssue(order[pi + 1]);
    panelMM();
    if (pi < 8){ if ((pi & 1) == 0) kEpi(pi >> 1); else vEpi(); }
    else qEpi(pi - 8);
    __syncthreads();
    if (pi < 8 && (pi & 1) == 1){ ctxPhase(pi >> 1); __syncthreads(); }
    if (pi < 11){ pfWrite(); __syncthreads(); }
  }
  if (tid < 256) sumwp[(size_t)blk * 256 + tid] = sumLds[tid];
}

// ---- K2: reduce ctx partials, normalize by sumw, fold Wout -> MT[b][j][hd] bf16 ----
__global__ __launch_bounds__(256) void k_build_m(const float* __restrict__ ctxp,
                                                 const float* __restrict__ sumwp,
                                                 const float* __restrict__ Wout,
                                                 unsigned short* __restrict__ MT){
  __shared__ float ctxs[32][33];
  __shared__ float swb[32];
  int b = blockIdx.x >> 3, h = blockIdx.x & 7;
  int t = threadIdx.x;
  int e = t & 31, dq = t >> 5;
  float a0 = 0.f, a1 = 0.f, a2 = 0.f, a3 = 0.f;
  #pragma unroll 8
  for (int cb = 0; cb < 128; cb++){
    const float* cp = ctxp + ((size_t)(b * 128 + cb) * 8 + h) * 1024;
    a0 += cp[dq * 32 + e];         a1 += cp[(dq + 8) * 32 + e];
    a2 += cp[(dq + 16) * 32 + e];  a3 += cp[(dq + 24) * 32 + e];
  }
  if (t < 32){
    float sw = 0.f;
    #pragma unroll 8
    for (int cb = 0; cb < 128; cb++)
      sw += sumwp[(size_t)(b * 128 + cb) * 256 + h * 32 + t];
    swb[t] = sw;
  }
  __syncthreads();
  ctxs[dq][e]      = a0 / swb[dq];
  ctxs[dq + 8][e]  = a1 / swb[dq + 8];
  ctxs[dq + 16][e] = a2 / swb[dq + 16];
  ctxs[dq + 24][e] = a3 / swb[dq + 24];
  __syncthreads();
  float s[32];
  #pragma unroll
  for (int d = 0; d < 32; d++) s[d] = 0.f;
  for (int ee = 0; ee < 32; ee++){
    float wv = Wout[(size_t)(h * 32 + ee) * 256 + t];
    #pragma unroll
    for (int d = 0; d < 32; d++) s[d] += ctxs[d][ee] * wv;
  }
  unsigned short* mp = MT + (size_t)b * 65536 + (size_t)t * 256 + h * 32;
  #pragma unroll
  for (int d8 = 0; d8 < 4; d8++){
    short8 pk;
    #pragma unroll
    for (int q = 0; q < 8; q++) pk[q] = (short)f2bf(s[d8 * 8 + q]);
    *reinterpret_cast<short8*>(mp + d8 * 8) = pk;
  }
}

// ---- K3: out = LN( qs @ MT^T ) * gamma ; 2048 blocks x 256 thr, 64 rows/block ----
// A frags direct from global Q (registers); B: 32 KB swizzled LDS panel per jb.
__global__ __launch_bounds__(256, 4) void k_out(const unsigned short* __restrict__ Qm,
                                                const unsigned short* __restrict__ MT,
                                                const float* __restrict__ gamma,
                                                float* __restrict__ out){
  __shared__ unsigned short Bs[64 * 256];  // 32 KB swizzled
  const int blk = blockIdx.x;
  const int b = blk >> 8;
  const size_t m0 = (size_t)blk * 64;
  const int tid = threadIdx.x, wave = tid >> 6, lane = tid & 63;
  const int lg = lane >> 4, li = lane & 15;

  short8 afrag[8];
  {
    const unsigned short* qr = Qm + (m0 + wave * 16 + li) * 256 + lg * 8;
    #pragma unroll
    for (int ks = 0; ks < 8; ks++)
      afrag[ks] = *reinterpret_cast<const short8*>(qr + ks * 32);
  }
  const char* mtb = (const char*)MT + (size_t)b * 131072;
  f32x4 acc[4][4];
  const f32x4 zf = {0.f, 0.f, 0.f, 0.f};
  #pragma unroll
  for (int jb = 0; jb < 4; jb++)
    #pragma unroll
    for (int j = 0; j < 4; j++) acc[jb][j] = zf;

  #pragma unroll
  for (int jb = 0; jb < 4; jb++){
    if (jb) __syncthreads();
    #pragma unroll
    for (int rr = 0; rr < 8; rr++){
      int L = rr * 4096 + tid * 16;
      int G = L ^ (((L >> 9) & 7) << 4);   // pre-swizzled source (rule 21)
      gload_lds16(mtb + (size_t)jb * 32768 + G, (char*)Bs + L);
    }
    __syncthreads();
    #pragma unroll
    for (int ks = 0; ks < 8; ks++)
      #pragma unroll
      for (int j = 0; j < 4; j++){
        int n = j * 16 + li;
        int L = n * 512 + (ks * 32 + lg * 8) * 2;
        short8 bb = *reinterpret_cast<const short8*>((const char*)Bs + (L ^ ((n & 7) << 4)));
        acc[jb][j] = __builtin_amdgcn_mfma_f32_16x16x32_bf16(afrag[ks], bb, acc[jb][j], 0, 0, 0);
      }
  }

  // LayerNorm epilogue (wave-local: wave owns its 16 rows fully)
  float gam[16];
  #pragma unroll
  for (int jb = 0; jb < 4; jb++)
    #pragma unroll
    for (int j = 0; j < 4; j++) gam[jb * 4 + j] = gamma[jb * 64 + j * 16 + li];
  #pragma unroll
  for (int r = 0; r < 4; r++){
    float s = 0.f, qq = 0.f;
    #pragma unroll
    for (int jb = 0; jb < 4; jb++)
      #pragma unroll
      for (int j = 0; j < 4; j++){ float v = acc[jb][j][r]; s += v; qq += v * v; }
    #pragma unroll
    for (int mm = 1; mm < 16; mm <<= 1){ s += __shfl_xor(s, mm); qq += __shfl_xor(qq, mm); }
    float mu = s * (1.f / 256.f);
    float var = qq * (1.f / 256.f) - mu * mu;
    float inv = rsqrtf(var + EPS);
    float* op = out + (m0 + wave * 16 + lg * 4 + r) * 256;
    #pragma unroll
    for (int jb = 0; jb < 4; jb++)
      #pragma unroll
      for (int j = 0; j < 4; j++)
        op[jb * 64 + j * 16 + li] = (acc[jb][j][r] - mu) * inv * gam[jb * 4 + j];
  }
}

extern "C" void kernel_launch(void* const* d_in, const int* in_sizes, int n_in,
                              void* d_out, int out_size, void* d_ws, size_t ws_size,
                              hipStream_t stream){
  const float* x     = (const float*)d_in[0];
  const float* Wqkv  = (const float*)d_in[1];
  const float* Wout  = (const float*)d_in[2];
  const float* gamma = (const float*)d_in[3];
  float* out = (float*)d_out;

  char* ws = (char*)d_ws;
  size_t off = 0;
  unsigned short* Q   = (unsigned short*)(ws + off); off += (size_t)BATCH * SEQ * 256 * 2;  // 67 MB
  unsigned short* WT  = (unsigned short*)(ws + off); off += (size_t)NQKV * DIN * 2;
  float* ctxp         = (float*)(ws + off);          off += (size_t)1024 * 8 * 1024 * 4;    // 33.5 MB
  float* sumwp        = (float*)(ws + off);          off += (size_t)1024 * 256 * 4;
  unsigned short* MT  = (unsigned short*)(ws + off); off += (size_t)BATCH * 65536 * 2;

  k_wt<<<(NQKV * DIN) / 256, 256, 0, stream>>>(Wqkv, WT);
  k_qkv<<<1024, 256, 0, stream>>>(x, WT, Q, ctxp, sumwp);
  k_build_m<<<64, 256, 0, stream>>>(ctxp, sumwp, Wout, MT);
  k_out<<<2048, 256, 0, stream>>>(Q, MT, gamma, out);
}